// Round 1
// baseline (215.097 us; speedup 1.0000x reference)
//
#include <hip/hip_runtime.h>

#define HH 384
#define WW 384
#define HWSZ (HH * WW)          // 147456
#define BATCH 2
#define CHN 64
#define NPLANES (BATCH * CHN)   // 128
#define STRIP 96
#define NSTRIPS 4               // STRIP*NSTRIPS == HH
#define NACC 11

__device__ __forceinline__ float wave_scan_incl(float v, int lane) {
#pragma unroll
    for (int d = 1; d < 64; d <<= 1) {
        float u = __shfl_up(v, d, 64);
        if (lane >= d) v += u;
    }
    return v;
}

// rowbox: sum over columns [t-w2, t+w2] of (zero-padded) row r, from its prefix in LDS.
__device__ __forceinline__ float rb(const float (*Pb)[WW], int r, int w2, int t) {
    if (r < 0 || r >= HH) return 0.f;
    const float* row = Pb[r & 31];
    int hi = t + w2; if (hi > WW - 1) hi = WW - 1;
    int lo = t - w2 - 1; int loc = lo < 0 ? 0 : lo;
    float vhi = row[hi];
    float vlo = row[loc];
    return vhi - ((lo >= 0) ? vlo : 0.f);
}

__global__ __launch_bounds__(384) void stats_kernel(const float* __restrict__ x,
                                                    float* __restrict__ partials) {
    __shared__ float Pb[32][WW];      // 48 KB ring of row prefix sums
    __shared__ float wtot[8];
    __shared__ float redbuf[6 * NACC];

    const int t = threadIdx.x;        // column
    const int lane = t & 63;
    const int wv = t >> 6;
    const int bid = blockIdx.x;
    const int p = bid >> 2;           // plane
    const int s = bid & 3;            // strip
    const int y0 = s * STRIP;
    const float* __restrict__ src = x + (size_t)p * HWSZ;

    const int W2S[3] = {15, 7, 3};

    // horizontal count inverses (constant per thread)
    float invcx[3];
#pragma unroll
    for (int i = 0; i < 3; ++i) {
        int w2 = W2S[i];
        int hi = t + w2; if (hi > WW - 1) hi = WW - 1;
        int lo = t - w2; if (lo < 0) lo = 0;
        invcx[i] = 1.0f / (float)(hi - lo + 1);
    }

    float bsum[3] = {0.f, 0.f, 0.f};
    float Aa[3] = {0.f, 0.f, 0.f};
    float Bb[3] = {0.f, 0.f, 0.f};
    float Cc[3] = {0.f, 0.f, 0.f};
    float T1 = 0.f, T2 = 0.f;

    const int R0 = y0 - 16;
    const int R1 = y0 + STRIP + 14;   // last row needed: (y0+STRIP-1)+15

    // depth-1 prefetch
    float a_cur = (R0 >= 0 && R0 < HH) ? src[R0 * WW + t] : 0.f;

    for (int r = R0; r <= R1; ++r) {
        int rn = r + 1;
        float a_next = (rn <= R1 && rn >= 0 && rn < HH) ? src[rn * WW + t] : 0.f;

        // block-wide inclusive prefix of this row
        float v = wave_scan_incl(a_cur, lane);
        if (lane == 63) wtot[wv] = v;
        __syncthreads();
        float off = 0.f;
#pragma unroll
        for (int w = 0; w < 5; ++w) off += (w < wv) ? wtot[w] : 0.f;
        float P = v + off;
        Pb[r & 31][t] = P;
        __syncthreads();

        if (r == y0 + 15) {
            // initialize running vertical boxsums for first output row y0
#pragma unroll
            for (int i = 0; i < 3; ++i) {
                int w2 = W2S[i];
                float sum = 0.f;
                for (int rr = y0 - w2; rr <= y0 + w2; ++rr) sum += rb(Pb, rr, w2, t);
                bsum[i] = sum;
            }
        } else if (r > y0 + 15) {
            int y = r - 15;
#pragma unroll
            for (int i = 0; i < 3; ++i) {
                int w2 = W2S[i];
                bsum[i] += rb(Pb, y + w2, w2, t) - rb(Pb, y - w2 - 1, w2, t);
            }
        }

        if (r >= y0 + 15) {
            int y = r - 15;
            // recover x[y][t] from the prefix ring
            const float* rowy = Pb[y & 31];
            int tm1 = t - 1; int tml = tm1 < 0 ? 0 : tm1;
            float ph = rowy[t];
            float pl = rowy[tml];
            float xv = ph - ((t > 0) ? pl : 0.f);
            T1 += xv;
            T2 = fmaf(xv, xv, T2);
#pragma unroll
            for (int i = 0; i < 3; ++i) {
                int w2 = W2S[i];
                int chi = y + w2; if (chi > HH - 1) chi = HH - 1;
                int clo = y - w2; if (clo < 0) clo = 0;
                float invcy = __builtin_amdgcn_rcpf((float)(chi - clo + 1));
                float m = bsum[i] * (invcy * invcx[i]);
                Aa[i] += m;
                Bb[i] = fmaf(xv, m, Bb[i]);
                Cc[i] = fmaf(m, m, Cc[i]);
            }
        }
        a_cur = a_next;
    }

    // block reduction of 11 accumulators (deterministic)
    float acc[NACC] = {Aa[0], Bb[0], Cc[0], Aa[1], Bb[1], Cc[1],
                       Aa[2], Bb[2], Cc[2], T1, T2};
#pragma unroll
    for (int k = 0; k < NACC; ++k) {
#pragma unroll
        for (int d = 32; d >= 1; d >>= 1) acc[k] += __shfl_xor(acc[k], d, 64);
    }
    if (lane == 0) {
#pragma unroll
        for (int k = 0; k < NACC; ++k) redbuf[wv * NACC + k] = acc[k];
    }
    __syncthreads();
    if (t < NACC) {
        float ssum = 0.f;
#pragma unroll
        for (int w = 0; w < 6; ++w) ssum += redbuf[w * NACC + t];
        partials[bid * NACC + t] = ssum;
    }
}

__global__ __launch_bounds__(128) void scales_kernel(const float* __restrict__ partials,
                                                     const float* __restrict__ tiny,
                                                     float* __restrict__ scales) {
    int p = threadIdx.x;
    if (p >= NPLANES) return;
    int b = p >> 6, c = p & 63;
    float acc[NACC];
#pragma unroll
    for (int k = 0; k < NACC; ++k) acc[k] = 0.f;
    for (int s = 0; s < NSTRIPS; ++s) {
#pragma unroll
        for (int k = 0; k < NACC; ++k)
            acc[k] += partials[(p * NSTRIPS + s) * NACC + k];
    }
    const float Nf = (float)HWSZ;
    const float invNm1 = 1.0f / (float)(HWSZ - 1);
    float T1 = acc[9], T2 = acc[10];
    float thr = tiny[c] + 1e-6f;
#pragma unroll
    for (int l = 0; l < 4; ++l) {
        float S, Q;
        if (l < 3) {
            S = T1 - acc[l * 3 + 0];
            Q = T2 - 2.f * acc[l * 3 + 1] + acc[l * 3 + 2];
        } else {
            S = T1;   // var(x - mean) == var(x)
            Q = T2;
        }
        float var = (Q - S * S / Nf) * invNm1;
        float sd = sqrtf(fmaxf(var, 0.f));
        sd = fmaxf(sd, thr);
        scales[(b * 4 + l) * CHN + c] = 1.0f / sd;
    }
}

__global__ __launch_bounds__(256) void out_kernel(const float* __restrict__ x,
                                                  const float* __restrict__ scales,
                                                  float* __restrict__ out) {
    const unsigned QP = HWSZ / 4;               // 36864 quads per plane
    const unsigned NQ = NPLANES * QP;           // 4718592
    unsigned stride = gridDim.x * blockDim.x;
    for (unsigned i = blockIdx.x * blockDim.x + threadIdx.x; i < NQ; i += stride) {
        unsigned plane = i / QP;
        unsigned q = i - plane * QP;
        unsigned b = plane >> 6, c = plane & 63;
        float4 v = reinterpret_cast<const float4*>(x)[i];
#pragma unroll
        for (int l = 0; l < 4; ++l) {
            float sc = scales[(b * 4 + l) * CHN + c];
            float4 o;
            o.x = v.x * sc; o.y = v.y * sc; o.z = v.z * sc; o.w = v.w * sc;
            reinterpret_cast<float4*>(out)[(size_t)((b * 4 + l) * CHN + c) * QP + q] = o;
        }
    }
}

extern "C" void kernel_launch(void* const* d_in, const int* in_sizes, int n_in,
                              void* d_out, int out_size, void* d_ws, size_t ws_size,
                              hipStream_t stream) {
    const float* x = (const float*)d_in[0];
    const float* tiny = (const float*)d_in[1];
    float* out = (float*)d_out;

    float* partials = (float*)d_ws;                         // 512*11 floats
    float* scales = partials + NPLANES * NSTRIPS * NACC;    // 512 floats

    stats_kernel<<<NPLANES * NSTRIPS, 384, 0, stream>>>(x, partials);
    scales_kernel<<<1, 128, 0, stream>>>(partials, tiny, scales);

    const unsigned NQ = NPLANES * (HWSZ / 4);
    unsigned blocks = (NQ + 255) / 256;                     // 18432, single pass
    out_kernel<<<blocks, 256, 0, stream>>>(x, scales, out);
}